// Round 11
// baseline (204.750 us; speedup 1.0000x reference)
//
#include <hip/hip_runtime.h>
#include <hip/hip_bf16.h>

#define NB 32
#define NA 1024
#define ND 128
#define TG 16

__device__ __forceinline__ float gelu_exact(float x) {
    return 0.5f * x * (1.0f + erff(x * 0.7071067811865476f));
}

// exact mul+add (no fma contraction) to match the np reference bit-for-bit
__device__ __forceinline__ float dist2(float ax, float ay, float bx, float by) {
    float dx = ax - bx, dy = ay - by;
    return __fadd_rn(__fmul_rn(dx, dx), __fmul_rn(dy, dy));
}

// ---------------------------------------------------------------------------
// Slot processor with COMPILE-TIME slot index S: cxy[S], readlane, and the
// t=S..15 rescan are all statically indexed -> guaranteed registers (the
// R4/R5 scratch-spill came from the runtime lower bound `for (t=s;...)`).
// Invariant: when slot S is processed, all bits < S of m are already 0 in
// every lane (each slot's while-loop exhausts that bit wave-wide before the
// outer sequence advances), so scanning t >= S only is exact.
// ---------------------------------------------------------------------------
template <int S>
__device__ __forceinline__ void proc_slot(const float2 (&cxy)[16], int (&asg)[16],
                                          unsigned &m, int &gid, float thr2) {
    unsigned long long cand;
    while ((cand = __ballot((m >> S) & 1u)) != 0ULL) {
        const int L = (int)__builtin_ctzll(cand);        // wave-uniform leader lane
        const float lx = __builtin_bit_cast(float,
            __builtin_amdgcn_readlane(__builtin_bit_cast(int, cxy[S].x), L));
        const float ly = __builtin_bit_cast(float,
            __builtin_amdgcn_readlane(__builtin_bit_cast(int, cxy[S].y), L));
        unsigned take = 0u;
#pragma unroll
        for (int t = S; t < 16; ++t) {                   // compile-time trip count
            const float d2 = dist2(cxy[t].x, cxy[t].y, lx, ly);
            const bool tk = (d2 < thr2) && ((m >> t) & 1u);
            if (tk) asg[t] = gid;                        // static index t
            take |= (tk ? 1u : 0u) << t;
        }
        m &= ~take;                                      // leader absorbed too (d2=0)
        ++gid;
    }
}

// ---------------------------------------------------------------------------
// Clustering: ONE WAVE per batch (<=1 block/CU: no SIMD issue contention,
// no inter-wave handoff). Point i -> slot i/64, lane i%64; greedy order =
// slot-major = index order. Block NB computes the MLP(0) row.
// ---------------------------------------------------------------------------
__global__ __launch_bounds__(64, 1) void cluster_kernel(
    const float2* __restrict__ coords, const int* __restrict__ mask,
    int* __restrict__ assigned, int* __restrict__ gcount,
    float* __restrict__ out_mask, float* __restrict__ out_a2g,
    const float* __restrict__ b1, const float* __restrict__ W2,
    const float* __restrict__ b2, float* __restrict__ empty_row)
{
    const int lane = threadIdx.x;

    if (blockIdx.x == NB) {
        // empty row = gelu(b1) @ W2 + b2
        __shared__ float h0s[ND];
        h0s[lane]      = gelu_exact(b1[lane]);
        h0s[lane + 64] = gelu_exact(b1[lane + 64]);
        __syncthreads();
        float a0 = b2[lane], a1 = b2[lane + 64];
        for (int k = 0; k < ND; ++k) {
            float h = h0s[k];
            a0 += h * W2[k * ND + lane];
            a1 += h * W2[k * ND + lane + 64];
        }
        empty_row[lane]      = a0;
        empty_row[lane + 64] = a1;
        return;
    }

    const int b = blockIdx.x;
    const float2* cb = coords + (b << 10);
    const int*    mb = mask + (b << 10);

    float2 cxy[16];
    int asg[16];
    unsigned m = 0;
#pragma unroll
    for (int s = 0; s < 16; ++s) {                 // static indices everywhere
        cxy[s] = cb[s * 64 + lane];                // coalesced 512B per slot
        int v = mb[s * 64 + lane];
        asg[s] = v ? -1 : -2;
        m |= (v ? 1u : 0u) << s;
    }

    const float thr2 = 0.05f * 0.05f;
    int gid = 0;
    proc_slot<0>(cxy, asg, m, gid, thr2);
    proc_slot<1>(cxy, asg, m, gid, thr2);
    proc_slot<2>(cxy, asg, m, gid, thr2);
    proc_slot<3>(cxy, asg, m, gid, thr2);
    proc_slot<4>(cxy, asg, m, gid, thr2);
    proc_slot<5>(cxy, asg, m, gid, thr2);
    proc_slot<6>(cxy, asg, m, gid, thr2);
    proc_slot<7>(cxy, asg, m, gid, thr2);
    proc_slot<8>(cxy, asg, m, gid, thr2);
    proc_slot<9>(cxy, asg, m, gid, thr2);
    proc_slot<10>(cxy, asg, m, gid, thr2);
    proc_slot<11>(cxy, asg, m, gid, thr2);
    proc_slot<12>(cxy, asg, m, gid, thr2);
    proc_slot<13>(cxy, asg, m, gid, thr2);
    proc_slot<14>(cxy, asg, m, gid, thr2);
    proc_slot<15>(cxy, asg, m, gid, thr2);

    int*   ab = assigned + (b << 10);
    float* o2 = out_a2g + (b << 10);
    float* o1 = out_mask + (b << 10);
#pragma unroll
    for (int s = 0; s < 16; ++s) {
        int i = s * 64 + lane;
        ab[i] = asg[s];
        o2[i] = (asg[s] == -2) ? -1.0f : (float)asg[s];
        o1[i] = (i < gid) ? 1.0f : 0.0f;
    }
    if (lane == 0) gcount[b] = gid;
}

// ---------------------------------------------------------------------------
// Flood-fill out0 with the MLP(0) row (heavy mlp blocks overwrite g < G) and
// zero the pool accumulators. Fully parallel, no LDS.
// ---------------------------------------------------------------------------
__global__ __launch_bounds__(256) void fill_kernel(
    const float* __restrict__ empty_row, float4* __restrict__ out0,
    float4* __restrict__ sums4, float* __restrict__ counts)
{
    const int idx = blockIdx.x * 256 + threadIdx.x;   // B*A*32 float4s
    float4 r = ((const float4*)empty_row)[idx & 31];
    out0[idx] = r;
    sums4[idx] = make_float4(0.f, 0.f, 0.f, 0.f);
    if (idx < NB * NA) counts[idx] = 0.0f;
}

// ---------------------------------------------------------------------------
// Pooling via flat global f32 atomics. One thread per (agent, dim-quad).
// ---------------------------------------------------------------------------
__global__ __launch_bounds__(256) void pool_kernel(
    const float4* __restrict__ emb, const int* __restrict__ assigned,
    float* __restrict__ sums, float* __restrict__ counts)
{
    const int idx = blockIdx.x * 256 + threadIdx.x;   // B*A*32 threads
    const int al = idx >> 5;                          // b*A + a
    const int dq = idx & 31;
    const int g = assigned[al];
    if (g < 0) return;
    const int b = al >> 10;
    float4 e = emb[(size_t)al * 32 + dq];
    float* s = sums + (((size_t)((b << 10) + g)) * ND) + dq * 4;
    atomicAdd(s + 0, e.x);
    atomicAdd(s + 1, e.y);
    atomicAdd(s + 2, e.z);
    atomicAdd(s + 3, e.w);
    if (dq == 0) atomicAdd(&counts[(b << 10) + g], 1.0f);
}

// ---------------------------------------------------------------------------
// 2-layer MLP on real groups only (g0 >= G blocks exit; fill covered them).
// ---------------------------------------------------------------------------
__global__ __launch_bounds__(256, 2) void mlp_kernel(
    const float* __restrict__ sums, const float* __restrict__ counts,
    const int* __restrict__ gcount,
    const float4* __restrict__ W1, const float* __restrict__ b1,
    const float4* __restrict__ W2, const float* __restrict__ b2,
    float* __restrict__ out0)
{
    const int b = blockIdx.y;
    const int g0 = blockIdx.x * TG;
    const int tid = threadIdx.x;
    if (g0 >= gcount[b]) return;
    float* ob = out0 + ((size_t)(b << 10) + g0) * ND;

    __shared__ float4 Wl[4096];      // 64 KB
    __shared__ float tok[TG][ND];    // 8 KB: tokens, then h

    {   // tokens = sums / max(cnt,1)   (rows g >= G were zeroed -> MLP(0))
        const float4* s4 = (const float4*)(sums + ((size_t)(b << 10) + g0) * ND);
        float4* tdst = (float4*)&tok[0][0];
#pragma unroll
        for (int i = 0; i < 2; ++i) {
            int l = tid + i * 256;           // 0..511, 32 float4 per group
            float c = fmaxf(counts[(b << 10) + g0 + (l >> 5)], 1.0f);
            float4 v = s4[l];
            tdst[l] = make_float4(v.x / c, v.y / c, v.z / c, v.w / c);
        }
    }
#pragma unroll
    for (int i = 0; i < 16; ++i) Wl[tid + i * 256] = W1[tid + i * 256];
    __syncthreads();

    const int jq = tid & 31;
    const int gs = tid >> 5;
    float acc[2][4];
#pragma unroll
    for (int jj = 0; jj < 4; ++jj) { acc[0][jj] = 0.0f; acc[1][jj] = 0.0f; }

#pragma unroll 4
    for (int dd = 0; dd < ND; ++dd) {
        float4 wv = Wl[dd * 32 + jq];
        float t0 = tok[gs][dd];
        float t1 = tok[gs + 8][dd];
        acc[0][0] += t0 * wv.x; acc[0][1] += t0 * wv.y;
        acc[0][2] += t0 * wv.z; acc[0][3] += t0 * wv.w;
        acc[1][0] += t1 * wv.x; acc[1][1] += t1 * wv.y;
        acc[1][2] += t1 * wv.z; acc[1][3] += t1 * wv.w;
    }
    float4 bb = ((const float4*)b1)[jq];
    __syncthreads();   // all layer-1 tok reads done before overwrite
    {
        float4 h;
        h.x = gelu_exact(acc[0][0] + bb.x);
        h.y = gelu_exact(acc[0][1] + bb.y);
        h.z = gelu_exact(acc[0][2] + bb.z);
        h.w = gelu_exact(acc[0][3] + bb.w);
        *(float4*)&tok[gs][jq * 4] = h;
        h.x = gelu_exact(acc[1][0] + bb.x);
        h.y = gelu_exact(acc[1][1] + bb.y);
        h.z = gelu_exact(acc[1][2] + bb.z);
        h.w = gelu_exact(acc[1][3] + bb.w);
        *(float4*)&tok[gs + 8][jq * 4] = h;
    }
#pragma unroll
    for (int i = 0; i < 16; ++i) Wl[tid + i * 256] = W2[tid + i * 256];
    __syncthreads();

#pragma unroll
    for (int jj = 0; jj < 4; ++jj) { acc[0][jj] = 0.0f; acc[1][jj] = 0.0f; }
#pragma unroll 4
    for (int dd = 0; dd < ND; ++dd) {
        float4 wv = Wl[dd * 32 + jq];
        float t0 = tok[gs][dd];
        float t1 = tok[gs + 8][dd];
        acc[0][0] += t0 * wv.x; acc[0][1] += t0 * wv.y;
        acc[0][2] += t0 * wv.z; acc[0][3] += t0 * wv.w;
        acc[1][0] += t1 * wv.x; acc[1][1] += t1 * wv.y;
        acc[1][2] += t1 * wv.z; acc[1][3] += t1 * wv.w;
    }
    float4 cbv = ((const float4*)b2)[jq];
    {
        float4 o;
        o.x = acc[0][0] + cbv.x; o.y = acc[0][1] + cbv.y;
        o.z = acc[0][2] + cbv.z; o.w = acc[0][3] + cbv.w;
        *(float4*)&ob[(size_t)gs * ND + jq * 4] = o;
        o.x = acc[1][0] + cbv.x; o.y = acc[1][1] + cbv.y;
        o.z = acc[1][2] + cbv.z; o.w = acc[1][3] + cbv.w;
        *(float4*)&ob[(size_t)(gs + 8) * ND + jq * 4] = o;
    }
}

extern "C" void kernel_launch(void* const* d_in, const int* in_sizes, int n_in,
                              void* d_out, int out_size, void* d_ws, size_t ws_size,
                              hipStream_t stream) {
    const float* emb    = (const float*)d_in[0];   // [B,A,D]
    const float* coords = (const float*)d_in[1];   // [B,A,2]
    const int*   mask   = (const int*)d_in[2];     // [B,A]
    const float* W1     = (const float*)d_in[3];   // [D,D]
    const float* b1     = (const float*)d_in[4];   // [D]
    const float* W2     = (const float*)d_in[5];   // [D,D]
    const float* b2     = (const float*)d_in[6];   // [D]

    float* out0 = (float*)d_out;                    // [B,A,D]
    float* out1 = out0 + (size_t)NB * NA * ND;      // group_mask
    float* out2 = out1 + (size_t)NB * NA;           // agent_to_group

    // workspace: sums, counts, assigned, gcount, empty_row
    float* ws_sums   = (float*)d_ws;                        // B*A*D
    float* ws_counts = ws_sums + (size_t)NB * NA * ND;      // B*A
    int*   ws_asg    = (int*)(ws_counts + (size_t)NB * NA); // B*A
    int*   ws_gcnt   = ws_asg + (size_t)NB * NA;            // B
    float* ws_empty  = (float*)(ws_gcnt + NB);              // D

    cluster_kernel<<<NB + 1, 64, 0, stream>>>(
        (const float2*)coords, mask, ws_asg, ws_gcnt,
        out1, out2, b1, W2, b2, ws_empty);
    fill_kernel<<<NB * NA * 32 / 256, 256, 0, stream>>>(
        ws_empty, (float4*)out0, (float4*)ws_sums, ws_counts);
    pool_kernel<<<NB * NA * 32 / 256, 256, 0, stream>>>(
        (const float4*)emb, ws_asg, ws_sums, ws_counts);
    mlp_kernel<<<dim3(NA / TG, NB), 256, 0, stream>>>(
        ws_sums, ws_counts, ws_gcnt,
        (const float4*)W1, b1, (const float4*)W2, b2, out0);
}